// Round 14
// baseline (187.318 us; speedup 1.0000x reference)
//
#include <hip/hip_runtime.h>
#include <math.h>

// VectorQuantizer: x (32768,64) f32, codebook (8192,64) f32, start/end/use_sk ints.
// Outputs concat: x_q_st (2097152 f32) | loss (1 f32) | indices (32768 as f32 values).
//
// R23 = R22 with vq_rescue SPLIT into vq_parse (phase A) + vq_eval (phase B) for
// counter attribution: the non-pass1 residue has been pinned at ~102us across four
// rounds while rescue never surfaced in the top-5; models say it should be ~10us.
// Each half now gets its own dur/occupancy/VALU/FETCH counters. Side-benefit: the
// two phase-A barriers + parsing leave eval's critical path; parse blocks run
// fully parallel. pass1/sc/loss BYTE-IDENTICAL to R22 (proven absmax 0).
//  vq_sc:    sc_k exact (pairwise-8 numpy replica, f32) + cb -> bf16 rows (K=64).
//  vq_pass1: 32x32x16 MFMA filter, block = 128 tokens x 1024 codes (eighth), wave
//            owns 32 tokens (lane pairs l/l^32 split rows of the same token).
//            Per (token,eighth): running local min; REGISTER sorted slots s0..s8
//            (key = mono-f16<<16|cid5, mask32); 32-bit bitmap of running-window
//            accepts. Chunk mask = bits with acc >= chunkmax - W/2 (== g_bf <=
//            chunkmin + W, R9 semantics). Marker flag (bit15 of rec[7]) iff
//            mv(s8) <= thr_final (EXACT >=9-in-final-window; slot7 preserved).
//            Token-major 64B records via LDS transpose; bmap plane-major.
//  vq_parse: 2048 blocks x 16 tokens. Reads each (token,eighth) 64B record ->
//            gthr = min+WINDOW -> per-token CODE list (~4 codes) + chunk jobs
//            (code-list overflow -> chunk job; marker pushes bmap&~slotbits;
//            KCAP=320 >= structural max -> NO brute-force path). Flushes compact
//            lists to global (gcnt/glst/gclst).
//  vq_eval:  2048 blocks x 16 tokens x 4 waves; wave owns tokens 4wv..4wv+3
//            (= one legacy partial group). Stage x rows + exact sx (one barrier),
//            then batched code eval at 2 lanes/code with the BIT-EXACT R1
//            numpy-replica arithmetic (j0-3/j4-7 split, tt = s03+s47 via
//            shfl_xor(.,1), IEEE-commutative); chunk jobs = 32-code passes;
//            lex-min (enc(d),k); fused epilogue with the EXACT legacy loss tree
//            (6x shfl_down, (s0+s1)+(s2+s3), partial[token>>2]).
// Exactness: ref argmin k*: g_bf(k*) <= chunkmin + 2*err_bf (1.6e-4) < chunkmin+W
// -> k* in its chunk's mask. Its chunk's mv <= gmin + budget < gthr -> chunk in
// slots (codes via mask, or chunk job on list overflow) or marker fires and
// (slot masks + bmap&~slotbits chunk jobs) cover it -> k* always evaluated
// exactly; range filtered by k in [s,e). Lex-min over a superset containing the
// reference argmin == reference.
// DO NOT change the exact-path arithmetic: inter-code d gaps are ~1 ulp of d.

#define N_E    8192
#define EDIM   64
#define NTOK   32768
#define NELEM  (NTOK * EDIM)
#define CSZ    32                  // chunk size
#define WINDOW 3e-4f
#define TTOK   128                 // pass-1 tokens per block
#define TCODE  1024                // pass-1 codes per block (eighth)
#define SROW   72                  // Cs stride (ushorts; 36 dwords == 4 mod 8)
#define TOKB   16                  // parse/eval tokens per block
#define CCAP   64                  // per-token code-list capacity
#define KCAP   320                 // per-token chunk-job capacity (>= 256+64)

typedef __attribute__((ext_vector_type(8)))  short          short8;
typedef __attribute__((ext_vector_type(8)))  unsigned short ushort8v;
typedef __attribute__((ext_vector_type(16))) float          f32x16;

__device__ __forceinline__ unsigned short f2bf(float f) {   // RTNE f32->bf16 bits
  unsigned int u = __float_as_uint(f);
  return (unsigned short)((u + 0x7FFFu + ((u >> 16) & 1u)) >> 16);
}
__device__ __forceinline__ unsigned short f2h(float f) {
  union { _Float16 h; unsigned short u; } cv; cv.h = (_Float16)f; return cv.u;
}
__device__ __forceinline__ float h2f(unsigned short b) {
  union { _Float16 h; unsigned short u; } cv; cv.u = b; return (float)cv.h;
}
__device__ __forceinline__ float max16(const f32x16 a) {   // v_max3-fusible chain
  float m = fmaxf(fmaxf(a[0], a[1]), a[2]);
  m = fmaxf(fmaxf(m, a[3]),  a[4]);
  m = fmaxf(fmaxf(m, a[5]),  a[6]);
  m = fmaxf(fmaxf(m, a[7]),  a[8]);
  m = fmaxf(fmaxf(m, a[9]),  a[10]);
  m = fmaxf(fmaxf(m, a[11]), a[12]);
  m = fmaxf(fmaxf(m, a[13]), a[14]);
  return fmaxf(m, a[15]);
}
// sx = np.sum(x*x) pairwise-8 replica (reads a 64-f32 row via float4*)
__device__ __forceinline__ float sx_of(const float4* xl4) {
#pragma clang fp contract(off)
  float a0=0,a1=0,a2=0,a3=0,a4=0,a5=0,a6=0,a7=0;
#pragma unroll
  for (int i = 0; i < 8; ++i) {
    float4 pA = xl4[2*i], pB = xl4[2*i+1];
    a0 += pA.x * pA.x; a1 += pA.y * pA.y; a2 += pA.z * pA.z; a3 += pA.w * pA.w;
    a4 += pB.x * pB.x; a5 += pB.y * pB.y; a6 += pB.z * pB.z; a7 += pB.w * pB.w;
  }
  return ((a0+a1) + (a2+a3)) + ((a4+a5) + (a6+a7));
}

// ---------------- sc (exact pairwise-8) + cb -> bf16 rows (K=64) --------------------
__global__ __launch_bounds__(256) void vq_sc(const float* __restrict__ cb,
                                             float* __restrict__ sc,
                                             unsigned short* __restrict__ cbf) {
#pragma clang fp contract(off)
  int r = blockIdx.x * 256 + threadIdx.x;
  const float4* c4 = (const float4*)(cb + (size_t)r * EDIM);
  float sval = sx_of(c4);
  sc[r] = sval;
  unsigned short* dst = cbf + (size_t)r * EDIM;
#pragma unroll
  for (int h = 0; h < 8; ++h) {
    float4 fA = c4[2*h], fB = c4[2*h+1];
    ushort8v o = {f2bf(fA.x), f2bf(fA.y), f2bf(fA.z), f2bf(fA.w),
                  f2bf(fB.x), f2bf(fB.y), f2bf(fB.z), f2bf(fB.w)};
    *(ushort8v*)&dst[h * 8] = o;
  }
}

// ---------------- pass 1: MFMA filter -> token-major slot/mask records --------------
// (byte-identical to R22)
__global__ __launch_bounds__(256, 4) void vq_pass1(
    const float* __restrict__ x, const unsigned short* __restrict__ cbf,
    unsigned int* __restrict__ cand, unsigned int* __restrict__ bmapb,
    const int* __restrict__ p_start, const int* __restrict__ p_end) {
  __shared__ unsigned short Cs[128 * SROW];     // 18432 B (reused as emit scratch)
  int tid = threadIdx.x;
  int tb = blockIdx.x;    // token split [0,256)
  int cbk = blockIdx.y;   // code split  [0,8)  (the "eighth")
  int s = *p_start, e = *p_end;
  const bool allfull = (cbk * TCODE >= s) && (cbk * TCODE + TCODE <= e);

  int lane = tid & 63, wv = tid >> 6;
  int half = lane >> 5, ln = lane & 31;
  int tokbase = wv * 32;                        // wave owns 32 tokens

  const ushort8v* cg0 = (const ushort8v*)(cbf + (size_t)cbk * TCODE * EDIM);
#pragma unroll
  for (int p = 0; p < 4; ++p) {
    int idx = tid + p * 256;
    int row = idx >> 3, h = idx & 7;
    *(ushort8v*)&Cs[row * SROW + h * 8] = cg0[idx];
  }

  short8 bfr[4];
  {
    const float* xrow =
        x + (size_t)(tb * TTOK + tokbase + ln) * EDIM + half * 8;
#pragma unroll
    for (int ks = 0; ks < 4; ++ks) {
      float4 fA = *(const float4*)(xrow + ks * 16);
      float4 fB = *(const float4*)(xrow + ks * 16 + 4);
      short8 v = {(short)f2bf(fA.x), (short)f2bf(fA.y), (short)f2bf(fA.z),
                  (short)f2bf(fA.w), (short)f2bf(fB.x), (short)f2bf(fB.y),
                  (short)f2bf(fB.z), (short)f2bf(fB.w)};
      bfr[ks] = v;
    }
  }
  __syncthreads();

  unsigned s0=~0u,s1=~0u,s2=~0u,s3=~0u,s4=~0u,s5=~0u,s6=~0u,s7=~0u,s8=~0u;
  unsigned m0=0,m1=0,m2=0,m3=0,m4=0,m5=0,m6=0,m7=0,m8=0;
  unsigned bmap = 0u;
  float lm = INFINITY;                          // running local min (pair-uniform)

  for (int nb = 0; nb < 8; ++nb) {
    ushort8v creg[4];
    if (nb < 7) {
      const ushort8v* cg =
          (const ushort8v*)(cbf + ((size_t)cbk * TCODE + (nb + 1) * 128) * EDIM);
#pragma unroll
      for (int p = 0; p < 4; ++p) creg[p] = cg[tid + p * 256];
    }
#pragma unroll
    for (int cp = 0; cp < 2; ++cp) {
      f32x16 acc[2];
#pragma unroll
      for (int c2 = 0; c2 < 2; ++c2) acc[c2] = (f32x16)0.0f;
#pragma unroll
      for (int ks = 0; ks < 4; ++ks)
#pragma unroll
        for (int c2 = 0; c2 < 2; ++c2) {
          int ct = cp * 2 + c2;
          short8 a = *(const short8*)&Cs[(ct*32 + ln) * SROW + ks*16 + half*8];
          acc[c2] = __builtin_amdgcn_mfma_f32_32x32x16_bf16(a, bfr[ks],
                                                            acc[c2], 0, 0, 0);
        }
#pragma unroll
      for (int c2 = 0; c2 < 2; ++c2) {
        int cidL = nb * 4 + cp * 2 + c2;
        float v;
        if (allfull) {
          v = max16(acc[c2]);
        } else {
          int c0 = cbk * TCODE + cidL * 32;
          bool full = (c0 >= s) && (c0 + 32 <= e);
          if (full) {
            v = max16(acc[c2]);
          } else {
            v = -INFINITY;
#pragma unroll
            for (int r = 0; r < 16; ++r) {
              int code = c0 + (r & 3) + 8 * (r >> 2) + 4 * half;
              if (code >= s && code < e) v = fmaxf(v, acc[c2][r]);
            }
          }
        }
        v = fmaxf(v, __shfl_xor(v, 32, 64));
        unsigned short hh = f2h(-2.0f * v);
        float mv = h2f(hh);
        lm = fminf(lm, mv);
        if (mv <= lm + WINDOW) {                 // pair-uniform accept: shfl safe
          bmap |= 1u << cidL;
          float t = v - WINDOW * 0.5f;
          unsigned b = 0;
#pragma unroll
          for (int r = 0; r < 16; ++r) {
            int pos = (r & 3) + 8 * (r >> 2) + 4 * half;
            if (acc[c2][r] >= t) b |= (1u << pos);
          }
          b |= __shfl_xor(b, 32, 64);
          unsigned mono = (unsigned)hh ^ ((hh & 0x8000u) ? 0xFFFFu : 0x8000u);
          unsigned p = (mono << 16) | (unsigned)cidL;
          unsigned pm = b;
          if (p < s8) {
#define INS2_(SK, SM) { bool lt_ = p < (SK); unsigned tk_ = (SK), tm_ = (SM); \
            if (lt_) { (SK) = p; (SM) = pm; p = tk_; pm = tm_; } }
            INS2_(s0,m0) INS2_(s1,m1) INS2_(s2,m2) INS2_(s3,m3) INS2_(s4,m4)
            INS2_(s5,m5) INS2_(s6,m6) INS2_(s7,m7) INS2_(s8,m8)
#undef INS2_
          }
        }
      }
    }
    __syncthreads();
    if (nb < 7) {
#pragma unroll
      for (int p = 0; p < 4; ++p) {
        int idx = tid + p * 256;
        int row = idx >> 3, h = idx & 7;
        *(ushort8v*)&Cs[row * SROW + h * 8] = creg[p];
      }
    }
    __syncthreads();
  }

  if (!half) {
    float thr = lm + WINDOW;
    unsigned rec[8], msk[8];
#define EMIT_(J, S, M) { unsigned mono_ = (S) >> 16; \
    unsigned hh_ = (mono_ & 0x8000u) ? (mono_ ^ 0x8000u) : (mono_ ^ 0xFFFFu); \
    float v_ = h2f((unsigned short)hh_); \
    rec[J] = (v_ <= thr) ? ((hh_ << 16) | ((S) & 0xFFFFu)) : 0xFFFFFFFFu; \
    msk[J] = (M); }
    EMIT_(0, s0, m0) EMIT_(1, s1, m1) EMIT_(2, s2, m2) EMIT_(3, s3, m3)
    EMIT_(4, s4, m4) EMIT_(5, s5, m5) EMIT_(6, s6, m6) EMIT_(7, s7, m7)
#undef EMIT_
    {
      unsigned mono_ = s8 >> 16;
      unsigned hh_ = (mono_ & 0x8000u) ? (mono_ ^ 0x8000u) : (mono_ ^ 0xFFFFu);
      float v8 = h2f((unsigned short)hh_);
      if (v8 <= thr) rec[7] |= 0x8000u;          // marker FLAG (slot7 preserved)
    }
    int tl = tokbase + ln;
    unsigned* eb = (unsigned*)Cs;
#pragma unroll
    for (int j = 0; j < 8; ++j) {
      eb[tl * 17 + j]     = rec[j];
      eb[tl * 17 + 8 + j] = msk[j];
    }
    bmapb[(size_t)cbk * NTOK + (tb * TTOK + tl)] = bmap;
  }
  __syncthreads();
#pragma unroll
  for (int p = 0; p < 2; ++p) {
    int idx = tid + p * 256;                     // [0, 512)
    int tl = idx >> 2, part = idx & 3;           // tl in [0, 128)
    const unsigned* src = (const unsigned*)Cs + tl * 17 + part * 4;
    uint4 v; v.x = src[0]; v.y = src[1]; v.z = src[2]; v.w = src[3];
    *(uint4*)(cand + (((size_t)(tb * TTOK + tl)) * 8 + cbk) * 16 + part * 4) = v;
  }
}

// ---------------- parse: records -> per-token code lists + chunk jobs (global) ------
__global__ __launch_bounds__(256) void vq_parse(
    const unsigned int* __restrict__ cand, const unsigned int* __restrict__ bmapb,
    unsigned int* __restrict__ gcnt, unsigned short* __restrict__ glst,
    unsigned short* __restrict__ gclst,
    const int* __restrict__ p_start, const int* __restrict__ p_end) {
  __shared__ unsigned short lst[TOKB][CCAP];
  __shared__ unsigned short clst[TOKB][KCAP];
  __shared__ int ccnt[TOKB], kcnt[TOKB];
  int tid = threadIdx.x;
  int blk = blockIdx.x;

  if (tid < TOKB) { ccnt[tid] = 0; kcnt[tid] = 0; }
#pragma unroll
  for (int p = 0; p < (TOKB * CCAP) / 256; ++p)   // sentinel-fill code list
    ((unsigned short*)lst)[tid + p * 256] = 0xFFFFu;
  __syncthreads();

  if (tid < 128) {
    // one (token, eighth) unit each; record = ONE contiguous 64B read
    int tl = tid >> 3, q = tid & 7;
    int gtok = blk * TOKB + tl;
    const uint4* rp = (const uint4*)(cand + ((size_t)gtok * 8 + q) * 16);
    uint4 A0 = rp[0], A1 = rp[1], M0 = rp[2], M1 = rp[3];
    unsigned rv[8] = {A0.x, A0.y, A0.z, A0.w, A1.x, A1.y, A1.z, A1.w};
    unsigned mk[8] = {M0.x, M0.y, M0.z, M0.w, M1.x, M1.y, M1.z, M1.w};
    float m = INFINITY;
#pragma unroll
    for (int j = 0; j < 8; ++j)                  // invalid slot -> hh=0xFFFF=NaN
      m = fminf(m, h2f((unsigned short)(rv[j] >> 16)));
    m = fminf(m, __shfl_xor(m, 1, 64));          // combine the token's 8 eighths
    m = fminf(m, __shfl_xor(m, 2, 64));
    m = fminf(m, __shfl_xor(m, 4, 64));
    float thr = m + WINDOW;
    bool marker = (rv[7] != 0xFFFFFFFFu) && ((rv[7] & 0x8000u) != 0u);
    unsigned slotbits = 0u;
#pragma unroll
    for (int j = 0; j < 8; ++j) {
      if (rv[j] != 0xFFFFFFFFu) {
        unsigned cid = rv[j] & 0x1Fu;            // low 5 bits (flag bit above)
        slotbits |= 1u << cid;
        if (h2f((unsigned short)(rv[j] >> 16)) <= thr) {
          unsigned bits = mk[j];
          int n = __popc(bits);
          int base = atomicAdd(&ccnt[tl], n);
          if (base + n <= CCAP) {                // push individual codes
            int kb = (q * 32 + (int)cid) * CSZ;
            while (bits) {
              int bpos = __ffs(bits) - 1; bits &= bits - 1;
              lst[tl][base++] = (unsigned short)(kb + bpos);
            }
          } else {                               // overflow: push whole chunk (exact)
            int kb2 = atomicAdd(&kcnt[tl], 1);
            if (kb2 < KCAP) clst[tl][kb2] = (unsigned short)(q * 32 + (int)cid);
          }
        }
      }
    }
    if (marker) {                                // non-slot accepted chunks -> jobs
      unsigned bm = bmapb[(size_t)q * NTOK + gtok] & ~slotbits;
      int n = __popc(bm);
      int base = atomicAdd(&kcnt[tl], n);
      while (bm) {
        int j = __ffs(bm) - 1; bm &= bm - 1;
        if (base < KCAP) clst[tl][base] = (unsigned short)(q * 32 + j);
        ++base;
      }
    }
  }
  __syncthreads();

  // ---- flush: gcnt (16), glst rows (128 uint4), gclst only up to kcnt ----
  if (tid < TOKB) {
    int kc = kcnt[tid]; if (kc > KCAP) kc = KCAP;
    gcnt[blk * TOKB + tid] = (unsigned)ccnt[tid] | ((unsigned)kc << 16);
  }
  if (tid < 128) {
    int tl = tid >> 3, part = tid & 7;           // 8 uint4 per 64-u16 row
    *(uint4*)(glst + ((size_t)(blk * TOKB + tl)) * CCAP + part * 8) =
        *(const uint4*)&lst[tl][part * 8];
  } else {
    int t2 = tid - 128;
    int tl = t2 >> 3, p0 = t2 & 7;
#pragma unroll
    for (int p = 0; p < 5; ++p) {                // KCAP=320 u16 = 40 uint4
      int part = p0 + p * 8;
      if (part * 8 < kcnt[tl] && part < 40)
        *(uint4*)(gclst + ((size_t)(blk * TOKB + tl)) * KCAP + part * 8) =
            *(const uint4*)&clst[tl][part * 8];
    }
  }
}

// ---------------- eval: batched exact code eval + fused epilogue --------------------
__global__ __launch_bounds__(256) void vq_eval(
    const float* __restrict__ x, const float* __restrict__ cb,
    const float* __restrict__ sc, const unsigned int* __restrict__ gcnt,
    const unsigned short* __restrict__ glst, const unsigned short* __restrict__ gclst,
    float* __restrict__ out_xq, float* __restrict__ out_idx,
    float* __restrict__ partial,
    const int* __restrict__ p_start, const int* __restrict__ p_end) {
#pragma clang fp contract(off)
  __shared__ float xsh[TOKB][64];
  __shared__ float sxs[TOKB];
  int tid  = threadIdx.x;
  int wv   = tid >> 6;
  int lane = tid & 63;
  int blk  = blockIdx.x;
  int s = *p_start, e = *p_end;

  // per-wave stage of its own 4 tokens (lane: token=lane>>4, seg=lane&15)
  {
    int ti = lane >> 4, seg = lane & 15;
    int tl = wv * 4 + ti;
    *(float4*)&xsh[tl][seg * 4] =
        ((const float4*)(x + (size_t)(blk * TOKB + tl) * EDIM))[seg];
  }
  __syncthreads();                               // xsh visible (also orders sxs)
  if (tid < TOKB) sxs[tid] = sx_of((const float4*)xsh[tid]);
  __syncthreads();

#define EVAL_CODE_BODY(K_, XL4) do {                                           \
    const float4* c4_ = (const float4*)(cb + (size_t)(K_) * EDIM);             \
    float t0_=0.0f,t1_=0.0f,t2_=0.0f,t3_=0.0f;                                 \
    _Pragma("unroll")                                                          \
    for (int i_ = 0; i_ < 8; ++i_) {             /* elements ascending i */    \
      float4 v_ = c4_[2*i_ + h5_];                                             \
      float4 p_ = (XL4)[2*i_ + h5_];                                           \
      t0_ += v_.x * p_.x; t1_ += v_.y * p_.y;                                  \
      t2_ += v_.z * p_.z; t3_ += v_.w * p_.w;                                  \
    }                                                                          \
    s2_ = (t0_ + t1_) + (t2_ + t3_);             /* s03 (h5=0) / s47 (h5=1) */ \
  } while (0)

#define FINISH_CODE(K_, ACT, SX, BP) do {                                      \
    float tt_ = s2_ + __shfl_xor(s2_, 1, 64);                                  \
    if ((ACT) && (K_) >= s && (K_) < e) {                                      \
      float d_ = ((SX) + sc[K_]) - 2.0f * tt_;                                 \
      unsigned db_ = __float_as_uint(d_);                                      \
      unsigned en_ = db_ ^ ((unsigned)((int)db_ >> 31) | 0x80000000u);         \
      unsigned long long pk_ = ((unsigned long long)en_ << 32) | (unsigned)(K_);\
      if (pk_ < (BP)) (BP) = pk_;                                              \
    }                                                                          \
  } while (0)

  float sg[4];
#pragma unroll
  for (int ti = 0; ti < 4; ++ti) {
    int tl = wv * 4 + ti;
    int gtok = blk * TOKB + tl;
    const float4* xl4 = (const float4*)xsh[tl];
    float sx = sxs[tl];
    unsigned cw = gcnt[gtok];
    int nc = (int)(cw & 0xFFFFu); if (nc > CCAP) nc = CCAP;
    int nk = (int)(cw >> 16);     if (nk > KCAP) nk = KCAP;
    unsigned long long bp = ~0ull;
    int ci_ = lane >> 1, h5_ = lane & 1;
    for (int b0 = 0; b0 < nc; b0 += 32) {        // usually exactly one batch
      int nb = nc - b0; if (nb > 32) nb = 32;
      int kraw = (ci_ < nb) ? (int)glst[(size_t)gtok * CCAP + b0 + ci_] : 0xFFFF;
      bool act = (kraw != 0xFFFF);               // sentinel = unwritten slot
      int k_ = act ? kraw : 0;
      float s2_ = 0.0f;
      if (act) EVAL_CODE_BODY(k_, xl4);
      FINISH_CODE(k_, act, sx, bp);
    }
    for (int i = 0; i < nk; ++i) {               // chunk jobs (bounded, no cliff)
      int k_ = (int)gclst[(size_t)gtok * KCAP + i] * CSZ + ci_;
      float s2_;
      EVAL_CODE_BODY(k_, xl4);
      FINISH_CODE(k_, true, sx, bp);
    }
#pragma unroll
    for (int off = 32; off >= 1; off >>= 1) {    // lex-min (d asc, k asc)
      unsigned long long o = __shfl_xor(bp, off, 64);
      if (o < bp) bp = o;
    }
    int bidx = (int)(unsigned)(bp & 0xFFFFFFFFull) & (N_E - 1);

    float xx = xsh[tl][lane];
    float qv = cb[(size_t)bidx * EDIM + lane];
    float diff = qv - xx;                              // fl(x_q - x)
    out_xq[(size_t)gtok * EDIM + lane] = xx + diff;    // fl(x + fl(x_q - x))
    if (lane == 0) out_idx[gtok] = (float)bidx;
    float l = diff * diff;
#pragma unroll
    for (int off = 32; off >= 1; off >>= 1) l += __shfl_down(l, off, 64);
    sg[ti] = l;                                  // legacy per-token tree
  }
#undef EVAL_CODE_BODY
#undef FINISH_CODE
  if (lane == 0)
    partial[blk * 4 + wv] = (sg[0] + sg[1]) + (sg[2] + sg[3]);
}

// ---------------- final loss reduction ----------------------------------------------
__global__ __launch_bounds__(256) void vq_loss(const float* __restrict__ partial,
                                               float* __restrict__ out_loss) {
  int tid = threadIdx.x;
  float s = 0.0f;
  for (int i = tid; i < NTOK / 4; i += 256) s += partial[i];
#pragma unroll
  for (int off = 32; off >= 1; off >>= 1) s += __shfl_down(s, off, 64);
  __shared__ float sdata[4];
  if ((tid & 63) == 0) sdata[tid >> 6] = s;
  __syncthreads();
  if (tid == 0) {
    float total = (sdata[0] + sdata[1]) + (sdata[2] + sdata[3]);
    float m = total * (1.0f / (float)NELEM);
    out_loss[0] = m + 0.25f * m;
  }
}

// ---------------- launch -------------------------------------------------------------
extern "C" void kernel_launch(void* const* d_in, const int* in_sizes, int n_in,
                              void* d_out, int out_size, void* d_ws, size_t ws_size,
                              hipStream_t stream) {
  const float* x  = (const float*)d_in[0];
  const float* cb = (const float*)d_in[1];
  const int* p_start = (const int*)d_in[2];
  const int* p_end   = (const int*)d_in[3];

  float* ws = (float*)d_ws;
  float* sc      = ws;                                            // 8192 f
  float* partial = ws + N_E;                                      // 8192 f
  unsigned short* cbf  = (unsigned short*)(ws + 2 * N_E);         // 1MB
  unsigned int*   cand = (unsigned int*)(cbf + (size_t)N_E * EDIM); // 16.8MB
  unsigned int*   bmapb = cand + (size_t)NTOK * 8 * 16;           // 1MB
  unsigned int*   gcnt  = bmapb + (size_t)NTOK * 8;               // 128KB
  unsigned short* glst  = (unsigned short*)(gcnt + NTOK);         // 4MB
  unsigned short* gclst = glst + (size_t)NTOK * CCAP;             // 21MB

  float* out      = (float*)d_out;
  float* out_xq   = out;                 // 2097152
  float* out_loss = out + NELEM;         // 1
  float* out_idx  = out + NELEM + 1;     // 32768

  vq_sc<<<N_E / 256, 256, 0, stream>>>(cb, sc, cbf);
  dim3 g1(NTOK / TTOK, N_E / TCODE);
  vq_pass1<<<g1, 256, 0, stream>>>(x, cbf, cand, bmapb, p_start, p_end);
  vq_parse<<<NTOK / TOKB, 256, 0, stream>>>(cand, bmapb, gcnt, glst, gclst,
                                            p_start, p_end);
  vq_eval<<<NTOK / TOKB, 256, 0, stream>>>(x, cb, sc, gcnt, glst, gclst,
                                           out_xq, out_idx, partial,
                                           p_start, p_end);
  vq_loss<<<1, 256, 0, stream>>>(partial, out_loss);
}

// Round 15
// 178.753 us; speedup vs baseline: 1.0479x; 1.0479x over previous
//
#include <hip/hip_runtime.h>
#include <math.h>

// VectorQuantizer: x (32768,64) f32, codebook (8192,64) f32, start/end/use_sk ints.
// Outputs concat: x_q_st (2097152 f32) | loss (1 f32) | indices (32768 as f32 values).
//
// R24: slot/mask/bitmap machinery DELETED. R17-R22 lesson: the accept branch is
// per-token but waves carry 32 tokens -> P(any lane accepts) ~ 1 -> the ~80-op
// mask+insert epilogue ran for every chunk under exec mask (VALUBusy 77%). Fix by
// removing the work: pass1 emits RAW per-chunk f16 minima (32 per (token,eighth)
// = 64B record, same layout/flush as R22); rescue computes thr = global-min + W
// over all 256 minima (NO truncation -> simpler exactness) and fully evaluates
// every surviving chunk (~2.6/token) with the batched bit-exact path.
//  vq_sc:    sc_k exact (pairwise-8 numpy replica, f32) + cb -> bf16 rows (K=64).
//  vq_pass1: 32x32x16 MFMA filter, block = 128 tokens x 1024 codes (eighth), wave
//            owns 32 tokens (lane pairs l/l^32 split rows of the same token).
//            Per chunk: masked max16 -> cross-half shfl merge -> f2h(-2v) -> one
//            u16 store to minL[128][34] (stride 17 dwords: conflict-free).
//            Flush: token-major 64B records (16 u32 = 32 f16, chunk cidL at u16
//            index cidL), coalesced uint4 stores.
//  vq_rescue: 2048 blocks x 16 tokens x 4 waves. Phase A: tid<128: one
//            (token,eighth) 64B record read -> min over 32 f16 -> shfl-combine 8
//            eighths -> thr = gmin + WINDOW -> push chunks with mv <= thr to LDS
//            list (KCAP=256 = structural max: NO overflow path). tid 128..191:
//            stage x rows; tid 192..207: exact sx (pairwise-8 replica). Phase B:
//            wave owns tokens 4wv..4wv+3 (= one legacy partial group): per
//            surviving chunk one 32-code batch at 2 lanes/code with the BIT-EXACT
//            R1 numpy-replica arithmetic (j0-3/j4-7 split, tt = s03+s47 via
//            shfl_xor(.,1), IEEE-commutative); lex-min (enc(d),k); fused epilogue
//            with the EXACT legacy loss tree (6x shfl_down, (s0+s1)+(s2+s3),
//            partial[token>>2]).
// Exactness: thr = min over ALL 256 f16 chunk minima + WINDOW (no slot truncation,
// no marker). Ref argmin k*: mv(chunk of k*) <= g_bf(k*) <= gmin + 2*err_bf +
// sc_max (1.6e-4 + 1e-6 < W=3e-4) -> its chunk always survives -> every in-range
// code of surviving chunks evaluated exactly -> lex-min over a superset containing
// the reference argmin == reference. Out-of-range chunks emit +inf (never survive);
// out-of-range codes filtered by k in [s,e).
// DO NOT change the exact-path arithmetic: inter-code d gaps are ~1 ulp of d.

#define N_E    8192
#define EDIM   64
#define NTOK   32768
#define NELEM  (NTOK * EDIM)
#define CSZ    32                  // chunk size
#define WINDOW 3e-4f
#define TTOK   128                 // pass-1 tokens per block
#define TCODE  1024                // pass-1 codes per block (eighth)
#define SROW   72                  // Cs stride (ushorts; 36 dwords == 4 mod 8)
#define TOKB   16                  // rescue tokens per block
#define KCAP   256                 // per-token chunk-list capacity (= structural max)

typedef __attribute__((ext_vector_type(8)))  short          short8;
typedef __attribute__((ext_vector_type(8)))  unsigned short ushort8v;
typedef __attribute__((ext_vector_type(16))) float          f32x16;

__device__ __forceinline__ unsigned short f2bf(float f) {   // RTNE f32->bf16 bits
  unsigned int u = __float_as_uint(f);
  return (unsigned short)((u + 0x7FFFu + ((u >> 16) & 1u)) >> 16);
}
__device__ __forceinline__ unsigned short f2h(float f) {
  union { _Float16 h; unsigned short u; } cv; cv.h = (_Float16)f; return cv.u;
}
__device__ __forceinline__ float h2f(unsigned short b) {
  union { _Float16 h; unsigned short u; } cv; cv.u = b; return (float)cv.h;
}
__device__ __forceinline__ float max16(const f32x16 a) {   // v_max3-fusible chain
  float m = fmaxf(fmaxf(a[0], a[1]), a[2]);
  m = fmaxf(fmaxf(m, a[3]),  a[4]);
  m = fmaxf(fmaxf(m, a[5]),  a[6]);
  m = fmaxf(fmaxf(m, a[7]),  a[8]);
  m = fmaxf(fmaxf(m, a[9]),  a[10]);
  m = fmaxf(fmaxf(m, a[11]), a[12]);
  m = fmaxf(fmaxf(m, a[13]), a[14]);
  return fmaxf(m, a[15]);
}
// sx = np.sum(x*x) pairwise-8 replica (reads a 64-f32 row via float4*)
__device__ __forceinline__ float sx_of(const float4* xl4) {
#pragma clang fp contract(off)
  float a0=0,a1=0,a2=0,a3=0,a4=0,a5=0,a6=0,a7=0;
#pragma unroll
  for (int i = 0; i < 8; ++i) {
    float4 pA = xl4[2*i], pB = xl4[2*i+1];
    a0 += pA.x * pA.x; a1 += pA.y * pA.y; a2 += pA.z * pA.z; a3 += pA.w * pA.w;
    a4 += pB.x * pB.x; a5 += pB.y * pB.y; a6 += pB.z * pB.z; a7 += pB.w * pB.w;
  }
  return ((a0+a1) + (a2+a3)) + ((a4+a5) + (a6+a7));
}

// ---------------- sc (exact pairwise-8) + cb -> bf16 rows (K=64) --------------------
__global__ __launch_bounds__(256) void vq_sc(const float* __restrict__ cb,
                                             float* __restrict__ sc,
                                             unsigned short* __restrict__ cbf) {
#pragma clang fp contract(off)
  int r = blockIdx.x * 256 + threadIdx.x;
  const float4* c4 = (const float4*)(cb + (size_t)r * EDIM);
  float sval = sx_of(c4);
  sc[r] = sval;
  unsigned short* dst = cbf + (size_t)r * EDIM;
#pragma unroll
  for (int h = 0; h < 8; ++h) {
    float4 fA = c4[2*h], fB = c4[2*h+1];
    ushort8v o = {f2bf(fA.x), f2bf(fA.y), f2bf(fA.z), f2bf(fA.w),
                  f2bf(fB.x), f2bf(fB.y), f2bf(fB.z), f2bf(fB.w)};
    *(ushort8v*)&dst[h * 8] = o;
  }
}

// ---------------- pass 1: MFMA filter -> raw per-chunk f16 minima records -----------
// Frags: A[m=lane&31][k=8*(lane>>5)+j] (codes), B same (tokens),
// D: col=lane&31 (token), row=(reg&3)+8*(reg>>2)+4*(lane>>5) (code).
// Record: cand[(token*8+q)*16 + w] holds chunks {2w (lo16), 2w+1 (hi16)}.
__global__ __launch_bounds__(256, 4) void vq_pass1(
    const float* __restrict__ x, const unsigned short* __restrict__ cbf,
    unsigned int* __restrict__ cand,
    const int* __restrict__ p_start, const int* __restrict__ p_end) {
  __shared__ unsigned short Cs[128 * SROW];     // 18432 B
  __shared__ unsigned minL[128 * 17];           // 8704 B (u16 idx: tl*34 + cidL)
  int tid = threadIdx.x;
  int tb = blockIdx.x;    // token split [0,256)
  int cbk = blockIdx.y;   // code split  [0,8)  (the "eighth")
  int s = *p_start, e = *p_end;
  const bool allfull = (cbk * TCODE >= s) && (cbk * TCODE + TCODE <= e);

  int lane = tid & 63, wv = tid >> 6;
  int half = lane >> 5, ln = lane & 31;
  int tokbase = wv * 32;                        // wave owns 32 tokens

  // ---- stage first code tile: 128 rows x 8 ushort8 (linear, coalesced) ----
  const ushort8v* cg0 = (const ushort8v*)(cbf + (size_t)cbk * TCODE * EDIM);
#pragma unroll
  for (int p = 0; p < 4; ++p) {
    int idx = tid + p * 256;
    int row = idx >> 3, h = idx & 7;
    *(ushort8v*)&Cs[row * SROW + h * 8] = cg0[idx];
  }

  // ---- B fragments straight from global (fused f32 -> bf16), own token group ----
  short8 bfr[4];
  {
    const float* xrow =
        x + (size_t)(tb * TTOK + tokbase + ln) * EDIM + half * 8;
#pragma unroll
    for (int ks = 0; ks < 4; ++ks) {
      float4 fA = *(const float4*)(xrow + ks * 16);
      float4 fB = *(const float4*)(xrow + ks * 16 + 4);
      short8 v = {(short)f2bf(fA.x), (short)f2bf(fA.y), (short)f2bf(fA.z),
                  (short)f2bf(fA.w), (short)f2bf(fB.x), (short)f2bf(fB.y),
                  (short)f2bf(fB.z), (short)f2bf(fB.w)};
      bfr[ks] = v;
    }
  }
  __syncthreads();

  unsigned short* minL16 = (unsigned short*)minL;

  for (int nb = 0; nb < 8; ++nb) {
    ushort8v creg[4];
    if (nb < 7) {                                // prefetch next tile into registers
      const ushort8v* cg =
          (const ushort8v*)(cbf + ((size_t)cbk * TCODE + (nb + 1) * 128) * EDIM);
#pragma unroll
      for (int p = 0; p < 4; ++p) creg[p] = cg[tid + p * 256];
    }
    // two ct-pair passes: {8-MFMA group -> 2-chunk epilogue-lite} (acc = 32 VGPRs)
#pragma unroll
    for (int cp = 0; cp < 2; ++cp) {
      f32x16 acc[2];
#pragma unroll
      for (int c2 = 0; c2 < 2; ++c2) acc[c2] = (f32x16)0.0f;
#pragma unroll
      for (int ks = 0; ks < 4; ++ks)
#pragma unroll
        for (int c2 = 0; c2 < 2; ++c2) {
          int ct = cp * 2 + c2;
          short8 a = *(const short8*)&Cs[(ct*32 + ln) * SROW + ks*16 + half*8];
          acc[c2] = __builtin_amdgcn_mfma_f32_32x32x16_bf16(a, bfr[ks],
                                                            acc[c2], 0, 0, 0);
        }
      // epilogue-lite: chunk max -> f16 minimum -> one u16 LDS store
#pragma unroll
      for (int c2 = 0; c2 < 2; ++c2) {
        int cidL = nb * 4 + cp * 2 + c2;         // local chunk id (0..31)
        float v;
        if (allfull) {                           // kernel-uniform fast path
          v = max16(acc[c2]);
        } else {
          int c0 = cbk * TCODE + cidL * 32;
          bool full = (c0 >= s) && (c0 + 32 <= e);
          if (full) {
            v = max16(acc[c2]);
          } else {
            v = -INFINITY;                       // fully-out chunk -> +inf record
#pragma unroll
            for (int r = 0; r < 16; ++r) {
              int code = c0 + (r & 3) + 8 * (r >> 2) + 4 * half;
              if (code >= s && code < e) v = fmaxf(v, acc[c2][r]);
            }
          }
        }
        v = fmaxf(v, __shfl_xor(v, 32, 64));     // chunk max (pair-merge, uniform)
        if (!half)                               // one u16 store per (token,chunk)
          minL16[(tokbase + ln) * 34 + cidL] = f2h(-2.0f * v);
      }
    }
    __syncthreads();                             // all Cs reads done
    if (nb < 7) {
#pragma unroll
      for (int p = 0; p < 4; ++p) {
        int idx = tid + p * 256;
        int row = idx >> 3, h = idx & 7;
        *(ushort8v*)&Cs[row * SROW + h * 8] = creg[p];
      }
    }
    __syncthreads();                             // Cs + minL writes visible
  }

  // ---- flush: 512 uint4 = 128 records x 4 full-line parts (coalesced) ----
#pragma unroll
  for (int p = 0; p < 2; ++p) {
    int idx = tid + p * 256;                     // [0, 512)
    int tl = idx >> 2, part = idx & 3;           // tl in [0, 128)
    const unsigned* src = minL + tl * 17 + part * 4;
    uint4 v; v.x = src[0]; v.y = src[1]; v.z = src[2]; v.w = src[3];
    *(uint4*)(cand + (((size_t)(tb * TTOK + tl)) * 8 + cbk) * 16 + part * 4) = v;
  }
}

// ---------------- pass 2: threshold + full-chunk exact eval + fused epilogue --------
__global__ __launch_bounds__(256) void vq_rescue(
    const float* __restrict__ x, const float* __restrict__ cb,
    const float* __restrict__ sc, const unsigned int* __restrict__ cand,
    float* __restrict__ out_xq, float* __restrict__ out_idx,
    float* __restrict__ partial,
    const int* __restrict__ p_start, const int* __restrict__ p_end) {
#pragma clang fp contract(off)
  __shared__ float xsh[TOKB][64];                 // 4 KB staged x rows
  __shared__ float sxs[TOKB];                     // exact sx per token
  __shared__ unsigned short clst[TOKB][KCAP];     // per-token surviving chunks (8 KB)
  __shared__ int kcnt[TOKB];
  int tid  = threadIdx.x;
  int wv   = tid >> 6;
  int lane = tid & 63;
  int blk  = blockIdx.x;
  int s = *p_start, e = *p_end;

  if (tid < TOKB) kcnt[tid] = 0;
  __syncthreads();

  // ---- phase A (split across waves; one barrier) --------------------------------
  if (tid < 128) {
    // waves 0-1: one (token, eighth) unit each; record = ONE contiguous 64B read
    int tl = tid >> 3, q = tid & 7;
    int gtok = blk * TOKB + tl;
    const uint4* rp = (const uint4*)(cand + ((size_t)gtok * 8 + q) * 16);
    uint4 A0 = rp[0], A1 = rp[1], A2 = rp[2], A3 = rp[3];
    unsigned rw[16] = {A0.x, A0.y, A0.z, A0.w, A1.x, A1.y, A1.z, A1.w,
                       A2.x, A2.y, A2.z, A2.w, A3.x, A3.y, A3.z, A3.w};
    float m = INFINITY;
#pragma unroll
    for (int j = 0; j < 16; ++j) {
      unsigned u = rw[j];
      m = fminf(m, fminf(h2f((unsigned short)(u & 0xFFFFu)),
                         h2f((unsigned short)(u >> 16))));
    }
    m = fminf(m, __shfl_xor(m, 1, 64));          // combine the token's 8 eighths
    m = fminf(m, __shfl_xor(m, 2, 64));
    m = fminf(m, __shfl_xor(m, 4, 64));
    float thr = m + WINDOW;                      // global window threshold
#pragma unroll
    for (int j = 0; j < 16; ++j) {
      unsigned u = rw[j];
      if (h2f((unsigned short)(u & 0xFFFFu)) <= thr) {
        int i = atomicAdd(&kcnt[tl], 1);
        if (i < KCAP) clst[tl][i] = (unsigned short)(q * 32 + 2 * j);
      }
      if (h2f((unsigned short)(u >> 16)) <= thr) {
        int i = atomicAdd(&kcnt[tl], 1);
        if (i < KCAP) clst[tl][i] = (unsigned short)(q * 32 + 2 * j + 1);
      }
    }
  } else if (tid < 192) {
    // wave 2: stage x rows (coalesced: 4 threads x 64B per 256B row)
    int t = tid - 128;                           // 0..63
#pragma unroll
    for (int p = 0; p < 4; ++p) {
      int idx = t + p * 64;                      // 0..255 float4 units
      int tl = idx >> 4, seg = idx & 15;
      *(float4*)&xsh[tl][seg * 4] =
          ((const float4*)(x + (size_t)(blk * TOKB + tl) * EDIM))[seg];
    }
  } else if (tid < 192 + TOKB) {
    // wave 3: exact sx per token (serial pairwise-8 replica, from global/L2)
    int tl = tid - 192;
    sxs[tl] = sx_of((const float4*)(x + (size_t)(blk * TOKB + tl) * EDIM));
  }
  __syncthreads();

  // exact single-code eval, 2 lanes/code: lane h5 covers t[4*h5..4*h5+3];
  // tt = s03 + s47 via shfl_xor(.,1) -- IEEE add commutative -> both lanes equal.
#define EVAL_CODE_BODY(K_, XL4) do {                                           \
    const float4* c4_ = (const float4*)(cb + (size_t)(K_) * EDIM);             \
    float t0_=0.0f,t1_=0.0f,t2_=0.0f,t3_=0.0f;                                 \
    _Pragma("unroll")                                                          \
    for (int i_ = 0; i_ < 8; ++i_) {             /* elements ascending i */    \
      float4 v_ = c4_[2*i_ + h5_];                                             \
      float4 p_ = (XL4)[2*i_ + h5_];                                           \
      t0_ += v_.x * p_.x; t1_ += v_.y * p_.y;                                  \
      t2_ += v_.z * p_.z; t3_ += v_.w * p_.w;                                  \
    }                                                                          \
    s2_ = (t0_ + t1_) + (t2_ + t3_);             /* s03 (h5=0) / s47 (h5=1) */ \
  } while (0)

#define FINISH_CODE(K_, ACT, SX, BP) do {                                      \
    float tt_ = s2_ + __shfl_xor(s2_, 1, 64);                                  \
    if ((ACT) && (K_) >= s && (K_) < e) {                                      \
      float d_ = ((SX) + sc[K_]) - 2.0f * tt_;                                 \
      unsigned db_ = __float_as_uint(d_);                                      \
      unsigned en_ = db_ ^ ((unsigned)((int)db_ >> 31) | 0x80000000u);         \
      unsigned long long pk_ = ((unsigned long long)en_ << 32) | (unsigned)(K_);\
      if (pk_ < (BP)) (BP) = pk_;                                              \
    }                                                                          \
  } while (0)

  // ---- phase B: wave wv owns tokens 4wv..4wv+3 (= one legacy partial group) -----
  float sg[4];
#pragma unroll
  for (int ti = 0; ti < 4; ++ti) {
    int tl = wv * 4 + ti;
    int gtok = blk * TOKB + tl;
    const float4* xl4 = (const float4*)xsh[tl];
    float sx = sxs[tl];
    unsigned long long bp = ~0ull;
    int ci_ = lane >> 1, h5_ = lane & 1;
    int nk = kcnt[tl]; if (nk > KCAP) nk = KCAP;
    for (int i = 0; i < nk; ++i) {               // ~2.6 full-chunk batches/token
      int k_ = (int)clst[tl][i] * CSZ + ci_;
      float s2_;
      EVAL_CODE_BODY(k_, xl4);
      FINISH_CODE(k_, true, sx, bp);
    }
#pragma unroll
    for (int off = 32; off >= 1; off >>= 1) {    // lex-min (d asc, k asc)
      unsigned long long o = __shfl_xor(bp, off, 64);
      if (o < bp) bp = o;
    }
    int bidx = (int)(unsigned)(bp & 0xFFFFFFFFull) & (N_E - 1);

    float xx = xsh[tl][lane];
    float qv = cb[(size_t)bidx * EDIM + lane];
    float diff = qv - xx;                              // fl(x_q - x)
    out_xq[(size_t)gtok * EDIM + lane] = xx + diff;    // fl(x + fl(x_q - x))
    if (lane == 0) out_idx[gtok] = (float)bidx;
    float l = diff * diff;
#pragma unroll
    for (int off = 32; off >= 1; off >>= 1) l += __shfl_down(l, off, 64);
    sg[ti] = l;                                  // legacy per-token tree
  }
#undef EVAL_CODE_BODY
#undef FINISH_CODE
  if (lane == 0)
    partial[blk * 4 + wv] = (sg[0] + sg[1]) + (sg[2] + sg[3]);
}

// ---------------- final loss reduction ----------------------------------------------
__global__ __launch_bounds__(256) void vq_loss(const float* __restrict__ partial,
                                               float* __restrict__ out_loss) {
  int tid = threadIdx.x;
  float s = 0.0f;
  for (int i = tid; i < NTOK / 4; i += 256) s += partial[i];
#pragma unroll
  for (int off = 32; off >= 1; off >>= 1) s += __shfl_down(s, off, 64);
  __shared__ float sdata[4];
  if ((tid & 63) == 0) sdata[tid >> 6] = s;
  __syncthreads();
  if (tid == 0) {
    float total = (sdata[0] + sdata[1]) + (sdata[2] + sdata[3]);
    float m = total * (1.0f / (float)NELEM);
    out_loss[0] = m + 0.25f * m;
  }
}

// ---------------- launch -------------------------------------------------------------
extern "C" void kernel_launch(void* const* d_in, const int* in_sizes, int n_in,
                              void* d_out, int out_size, void* d_ws, size_t ws_size,
                              hipStream_t stream) {
  const float* x  = (const float*)d_in[0];
  const float* cb = (const float*)d_in[1];
  const int* p_start = (const int*)d_in[2];
  const int* p_end   = (const int*)d_in[3];

  float* ws = (float*)d_ws;
  float* sc      = ws;                                            // 8192 f
  float* partial = ws + N_E;                                      // 8192 f
  unsigned short* cbf  = (unsigned short*)(ws + 2 * N_E);         // 1MB
  unsigned int*   cand = (unsigned int*)(cbf + (size_t)N_E * EDIM); // 16.8MB

  float* out      = (float*)d_out;
  float* out_xq   = out;                 // 2097152
  float* out_loss = out + NELEM;         // 1
  float* out_idx  = out + NELEM + 1;     // 32768

  vq_sc<<<N_E / 256, 256, 0, stream>>>(cb, sc, cbf);
  dim3 g1(NTOK / TTOK, N_E / TCODE);
  vq_pass1<<<g1, 256, 0, stream>>>(x, cbf, cand, p_start, p_end);
  vq_rescue<<<NTOK / TOKB, 256, 0, stream>>>(x, cb, sc, cand, out_xq, out_idx,
                                             partial, p_start, p_end);
  vq_loss<<<1, 256, 0, stream>>>(partial, out_loss);
}